// Round 13
// baseline (798.513 us; speedup 1.0000x reference)
//
#include <hip/hip_runtime.h>
#include <hip/hip_bf16.h>

// R-GCN 2-layer forward, round-15: FUSED aggregate+GEMM v3.
// r7 fusion failed on 9 barrier-phases; r12 failed on PER-THREAD gather (16B
// scattered loads -> FETCH 207MB). v3 keeps r12's one-barrier BM=16 skeleton
// but gathers with the PROVEN unit-per-segment pattern from the split
// aggregate (16-lane unit, lane l reads us8 at row*D+l*8 = one coalesced
// 256B row per instr, 4TB/s demonstrated): 16 units x 8 (node,rel) segments,
// f32 reg accumulate, swizzled LDS A-panel [16x1152] (36.9KB, 4 WG/CU),
// one barrier, then 36 K-step MFMA with B direct from L2-hot Bt.
// Deletes aggregate_kernel, gemm_kernel, the 102MB ACC buffer, and chunking
// (~870MB of HBM-level ACC traffic). Sort + cast unchanged from round-10.

#define D 128
#define KTOT 1152
#define BSH 9            // log2(coarse bucket size in nodes)
#define BSZ 512          // nodes per coarse bucket
#define TILE 4096        // edges per scatterA WG

typedef __attribute__((ext_vector_type(8))) __bf16 bf16x8;
typedef __attribute__((ext_vector_type(8))) unsigned short us8;
typedef __attribute__((ext_vector_type(4))) unsigned short us4;
typedef __attribute__((ext_vector_type(4))) float f32x4;

__device__ __forceinline__ unsigned short f2bf(float f) {
    union { float f; unsigned u; } v; v.f = f;
    unsigned r = v.u + 0x7FFF + ((v.u >> 16) & 1);   // RNE
    return (unsigned short)(r >> 16);
}
__device__ __forceinline__ float bf2f(unsigned short u) {
    return __uint_as_float((unsigned)u << 16);
}

// Fused LDS A-panel offset (in shorts): row-major 16 rows x 9 slices x 16
// chunks(16B); chunk XOR-swizzled by (row+slice) so both the unit-write
// (16 lanes, one row-slice) and the MFMA read (16 rows, one chunk) hit the
// minimum bank aliasing.
__device__ __forceinline__ int aoff(int row, int rr, int chunk) {
    return (row * 144 + rr * 16 + (chunk ^ ((row + rr) & 15))) * 8;
}

// ---------------- sort pass A: coarse-bucket histogram / scan / tile-sorted scatter ----------------

__global__ __launch_bounds__(256) void histA_kernel(const int* __restrict__ dst,
                                                    int* __restrict__ bcnt, int E, int nbuck) {
    __shared__ int c[1024];
    int t = threadIdx.x;
    for (int i = t; i < nbuck; i += 256) c[i] = 0;
    __syncthreads();
    int stride = gridDim.x * 256;
    for (int e = blockIdx.x * 256 + t; e < E; e += stride)
        atomicAdd(&c[dst[e] >> BSH], 1);
    __syncthreads();
    for (int i = t; i < nbuck; i += 256)
        if (c[i]) atomicAdd(&bcnt[i], c[i]);
}

__global__ __launch_bounds__(1024) void scanA_kernel(const int* __restrict__ bcnt,
                                                     int* __restrict__ boffs,
                                                     int* __restrict__ bhead, int nbuck) {
    int t = threadIdx.x;
    int v = (t < nbuck) ? bcnt[t] : 0;
    int lane = t & 63, w = t >> 6;
    int inc = v;
    #pragma unroll
    for (int off = 1; off < 64; off <<= 1) {
        int n = __shfl_up(inc, off, 64);
        if (lane >= off) inc += n;
    }
    __shared__ int ws[16];
    if (lane == 63) ws[w] = inc;
    __syncthreads();
    int wbase = 0;
    for (int i = 0; i < w; ++i) wbase += ws[i];
    int ex = wbase + inc - v;
    if (t < nbuck) { boffs[t] = ex; bhead[t] = ex; }
    if (t == nbuck - 1) boffs[nbuck] = ex + v;
}

// tile = 4096 edges per WG, 1024 threads (4 edges/thread): LDS counting-sort by
// coarse bucket, then write the reordered tile in per-bucket runs (~21 edges).
__global__ __launch_bounds__(1024) void scatterA_kernel(const int* __restrict__ src,
                                                        const int* __restrict__ dst,
                                                        const int* __restrict__ et,
                                                        int* __restrict__ bhead,
                                                        int* __restrict__ sortedA, int E, int nbuck) {
    __shared__ int skey[TILE];
    __shared__ unsigned char sbkt[TILE];
    __shared__ int cnt[256];
    __shared__ int lpos[256];
    __shared__ int gdelta[256];
    __shared__ int ws[4];
    const int t = threadIdx.x;
    const int e0 = blockIdx.x * TILE;
    int dreg[4];

    if (t < 256) cnt[t] = 0;
    __syncthreads();
    #pragma unroll
    for (int j = 0; j < 4; ++j) {
        int e = e0 + j * 1024 + t;
        int d = -1;
        if (e < E) { d = dst[e]; atomicAdd(&cnt[d >> BSH], 1); }
        dreg[j] = d;
    }
    __syncthreads();
    int c = 0, inc = 0;
    const int lane = t & 63, w = t >> 6;
    if (t < 256) {
        c = cnt[t];
        inc = c;
        #pragma unroll
        for (int off = 1; off < 64; off <<= 1) {
            int n = __shfl_up(inc, off, 64);
            if (lane >= off) inc += n;
        }
        if (lane == 63) ws[w] = inc;
    }
    __syncthreads();
    if (t < 256) {
        int wbase = 0;
        for (int i = 0; i < w; ++i) wbase += ws[i];
        int ex = wbase + inc - c;
        lpos[t] = ex;
        if (c) gdelta[t] = atomicAdd(&bhead[t], c) - ex;
    }
    __syncthreads();
    #pragma unroll
    for (int j = 0; j < 4; ++j) {
        int e = e0 + j * 1024 + t;
        if (e < E) {
            int d = dreg[j];
            int b = d >> BSH;
            int key = ((d & (BSZ - 1)) << 20) | (et[e] << 17) | src[e];
            int p = atomicAdd(&lpos[b], 1);
            skey[p] = key;
            sbkt[p] = (unsigned char)b;
        }
    }
    __syncthreads();
    int ntile = min(TILE, E - e0);
    for (int i = t; i < ntile; i += 1024)
        sortedA[gdelta[sbkt[i]] + i] = skey[i];
}

// ---------------- sort pass B: per-bucket fine sort by (node,rel) -> offs2[] + sorted[] ----------------

__global__ __launch_bounds__(256) void passB_kernel(const int* __restrict__ sortedA,
                                                    const int* __restrict__ boffs,
                                                    int* __restrict__ sorted,
                                                    int* __restrict__ offs2,
                                                    int N8, int E, int nbuck) {
    __shared__ int cnt[4096];
    __shared__ int cur[4096];
    __shared__ int ws[4];
    const int b = blockIdx.x;
    const int t = threadIdx.x;
    const int gb0 = boffs[b], gb1 = boffs[b + 1];
    #pragma unroll
    for (int i = 0; i < 16; ++i) cnt[i * 256 + t] = 0;
    __syncthreads();
    for (int e = gb0 + t; e < gb1; e += 256) {
        int k = sortedA[e];
        atomicAdd(&cnt[(k >> 17) & 4095], 1);   // (dst_low << 3) | etype
    }
    __syncthreads();
    const int base = t * 16;
    int s = 0;
    #pragma unroll
    for (int i = 0; i < 16; ++i) s += cnt[base + i];
    int lane = t & 63, w = t >> 6;
    int inc = s;
    #pragma unroll
    for (int off = 1; off < 64; off <<= 1) {
        int n = __shfl_up(inc, off, 64);
        if (lane >= off) inc += n;
    }
    if (lane == 63) ws[w] = inc;
    __syncthreads();
    int wbase = 0;
    for (int i = 0; i < w; ++i) wbase += ws[i];
    int run = gb0 + wbase + inc - s;
    int g0 = (b << 12) + base;
    #pragma unroll
    for (int i = 0; i < 16; ++i) {
        int cv = cnt[base + i];
        cur[base + i] = run;
        if (g0 + i <= N8) offs2[g0 + i] = run;
        run += cv;
    }
    __syncthreads();
    // final scatter: all writes land inside this bucket's ~32KB window (L2-hot) -> no amplification
    for (int e = gb0 + t; e < gb1; e += 256) {
        int k = sortedA[e];
        int p = atomicAdd(&cur[(k >> 17) & 4095], 1);
        sorted[p] = k;
    }
}

// ---------------- combined cast: Bt[o][k] bf16 (both layers) + hb0 bf16 ----------------

__global__ void cast_kernel(const float* __restrict__ W1, const float* __restrict__ lw1,
                            const float* __restrict__ W2, const float* __restrict__ lw2,
                            const float* __restrict__ feats,
                            unsigned short* __restrict__ Bt1, unsigned short* __restrict__ Bt2,
                            unsigned short* __restrict__ hb0, int n4) {
    const int per = KTOT * D;          // 147456
    int idx = blockIdx.x * blockDim.x + threadIdx.x;
    if (idx < 2 * per) {
        int layer = idx / per;
        int rem = idx - layer * per;
        int k = rem >> 7;
        int o = rem & 127;             // coalesced read dim
        const float* W  = layer ? W2 : W1;
        const float* lw = layer ? lw2 : lw1;
        float val = (k < 1024) ? W[k * D + o] : lw[(k - 1024) * D + o];
        unsigned short* Bt = layer ? Bt2 : Bt1;
        Bt[o * KTOT + k] = f2bf(val);
    } else {
        int i = idx - 2 * per;
        if (i < n4) {
            float4 v = *(const float4*)(feats + (size_t)i * 4);
            us4 o; o.x = f2bf(v.x); o.y = f2bf(v.y); o.z = f2bf(v.z); o.w = f2bf(v.w);
            *(us4*)(hb0 + (size_t)i * 4) = o;
        }
    }
}

// ---------------- FUSED aggregate + GEMM (v3) ----------------
// WG = 256 thr = 16 node rows. Gather: 16 units of 16 lanes; unit u owns
// segments seg = u + 16*j (j=0..7), seg = node*8 + rel; lane l covers cols
// [l*8, l*8+8) -> one coalesced 256B row read per edge per unit (proven
// aggregate pattern). Self-loop slice: unit u copies row v0+u. ONE barrier.
// MFMA: wave w owns cols [w*32, w*32+32); 36 K-steps; A from swizzled LDS,
// B direct from L2-resident Bt.

__global__ __launch_bounds__(256, 4) void fused_kernel(const unsigned short* __restrict__ hb,
                                                       const int* __restrict__ offs2,
                                                       const int* __restrict__ sorted,
                                                       const unsigned short* __restrict__ Bt,
                                                       const float* __restrict__ bias,
                                                       float* __restrict__ outf,
                                                       unsigned short* __restrict__ outb,
                                                       int N, int relu_bf) {
    __shared__ unsigned short Asl[16 * 144 * 8];   // 36864 B
    const int t = threadIdx.x;
    const int v0 = blockIdx.x * 16;
    const int u = t >> 4;              // unit 0..15
    const int l = t & 15;              // lane within unit; cols [l*8, l*8+8)

    // ---- gather phase: 8 segments per unit, coalesced 256B row reads ----
    for (int j = 0; j < 8; ++j) {
        const int seg = u + 16 * j;    // = node*8 + rel
        const int n = seg >> 3;
        const int r = seg & 7;
        const int v = v0 + n;
        float a0[8], a1[8];
        #pragma unroll
        for (int q = 0; q < 8; ++q) { a0[q] = 0.f; a1[q] = 0.f; }
        if (v < N) {
            int e0 = offs2[v * 8 + r], e1 = offs2[v * 8 + r + 1];
            int e = e0;
            for (; e + 1 < e1; e += 2) {
                int p0 = sorted[e], p1 = sorted[e + 1];
                us8 h0 = *(const us8*)(hb + (size_t)(p0 & 131071) * D + l * 8);
                us8 h1 = *(const us8*)(hb + (size_t)(p1 & 131071) * D + l * 8);
                #pragma unroll
                for (int q = 0; q < 8; ++q) { a0[q] += bf2f(h0[q]); a1[q] += bf2f(h1[q]); }
            }
            if (e < e1) {
                int p0 = sorted[e];
                us8 h0 = *(const us8*)(hb + (size_t)(p0 & 131071) * D + l * 8);
                #pragma unroll
                for (int q = 0; q < 8; ++q) a0[q] += bf2f(h0[q]);
            }
        }
        us8 o;
        #pragma unroll
        for (int q = 0; q < 8; ++q) o[q] = f2bf(a0[q] + a1[q]);
        *(us8*)(Asl + aoff(n, r, l)) = o;
    }
    // self-loop slice (rr=8): unit u copies row v0+u
    {
        const int v = v0 + u;
        us8 hv = {0, 0, 0, 0, 0, 0, 0, 0};
        if (v < N) hv = *(const us8*)(hb + (size_t)v * D + l * 8);
        *(us8*)(Asl + aoff(u, 8, l)) = hv;
    }
    __syncthreads();

    // ---- MFMA phase ----
    const int lane = t & 63;
    const int w = t >> 6;
    const int quad = lane >> 4;
    const int c16 = lane & 15;
    f32x4 acc[2];
    acc[0] = f32x4{0.f, 0.f, 0.f, 0.f};
    acc[1] = f32x4{0.f, 0.f, 0.f, 0.f};
    const unsigned short* B0 = Bt + (size_t)(w * 32 + c16) * KTOT + quad * 8;
    const unsigned short* B1 = Bt + (size_t)(w * 32 + 16 + c16) * KTOT + quad * 8;

    #pragma unroll
    for (int rr = 0; rr < 9; ++rr) {
        #pragma unroll
        for (int ks = 0; ks < 4; ++ks) {
            bf16x8 af = *(const bf16x8*)(Asl + aoff(c16, rr, ks * 4 + quad));
            const int kb = rr * 128 + ks * 32;
            bf16x8 b0 = *(const bf16x8*)(B0 + kb);
            bf16x8 b1 = *(const bf16x8*)(B1 + kb);
            acc[0] = __builtin_amdgcn_mfma_f32_16x16x32_bf16(af, b0, acc[0], 0, 0, 0);
            acc[1] = __builtin_amdgcn_mfma_f32_16x16x32_bf16(af, b1, acc[1], 0, 0, 0);
        }
    }

    // epilogue: C[row=quad*4+i][col=c16] per 16x16 tile (verified layout)
    int row0 = v0 + quad * 4;
    #pragma unroll
    for (int ct = 0; ct < 2; ++ct) {
        int col = w * 32 + ct * 16 + c16;
        float bcol = bias[col];
        #pragma unroll
        for (int i = 0; i < 4; ++i) {
            int r = row0 + i;
            if (r < N) {
                float vv = acc[ct][i] + bcol;
                if (relu_bf) {
                    vv = fmaxf(vv, 0.f);
                    outb[(size_t)r * D + col] = f2bf(vv);
                } else {
                    outf[(size_t)r * D + col] = vv;
                }
            }
        }
    }
}

// ---------------- launch ----------------

extern "C" void kernel_launch(void* const* d_in, const int* in_sizes, int n_in,
                              void* d_out, int out_size, void* d_ws, size_t ws_size,
                              hipStream_t stream) {
    const float* feats = (const float*)d_in[0];
    const float* W1    = (const float*)d_in[1];
    const float* lw1   = (const float*)d_in[2];
    const float* b1    = (const float*)d_in[3];
    const float* W2    = (const float*)d_in[4];
    const float* lw2   = (const float*)d_in[5];
    const float* b2    = (const float*)d_in[6];
    const int*   src   = (const int*)d_in[7];
    const int*   dst   = (const int*)d_in[8];
    const int*   etype = (const int*)d_in[9];
    const int N = in_sizes[0] / D;
    const int E = in_sizes[7];
    float* out = (float*)d_out;

    const int nbuck = (N + BSZ - 1) >> BSH;

    size_t woff = 0;
    auto take = [&](size_t bytes) -> void* {
        void* p = (char*)d_ws + woff;
        woff += (bytes + 255) & ~(size_t)255;
        return p;
    };
    int* bcnt           = (int*)take((size_t)1024 * 4);
    int* boffs          = (int*)take((size_t)1025 * 4);
    int* bhead          = (int*)take((size_t)1024 * 4);
    int* offs2          = (int*)take((size_t)(N * 8 + 1) * 4);
    int* sortedA        = (int*)take((size_t)E * 4);
    int* sorted         = (int*)take((size_t)E * 4);
    unsigned short* Bt1 = (unsigned short*)take((size_t)KTOT * D * 2);
    unsigned short* Bt2 = (unsigned short*)take((size_t)KTOT * D * 2);
    unsigned short* hb0 = (unsigned short*)take((size_t)N * D * 2);
    unsigned short* hb1 = (unsigned short*)take((size_t)N * D * 2);

    (void)hipMemsetAsync(bcnt, 0, (size_t)nbuck * 4, stream);

    histA_kernel<<<1024, 256, 0, stream>>>(dst, bcnt, E, nbuck);
    scanA_kernel<<<1, 1024, 0, stream>>>(bcnt, boffs, bhead, nbuck);
    scatterA_kernel<<<(E + TILE - 1) / TILE, 1024, 0, stream>>>(src, dst, etype, bhead, sortedA, E, nbuck);
    passB_kernel<<<nbuck, 256, 0, stream>>>(sortedA, boffs, sorted, offs2, N * 8, E, nbuck);

    int n4 = N * D / 4;
    int cb = (2 * KTOT * D + n4 + 255) / 256;
    cast_kernel<<<cb, 256, 0, stream>>>(W1, lw1, W2, lw2, feats, Bt1, Bt2, hb0, n4);

    int fb = (N + 15) / 16;
    fused_kernel<<<fb, 256, 0, stream>>>(hb0, offs2, sorted, Bt1, b1, nullptr, hb1, N, 1);
    fused_kernel<<<fb, 256, 0, stream>>>(hb1, offs2, sorted, Bt2, b2, out, nullptr, N, 0);
}

// Round 14
// 522.115 us; speedup vs baseline: 1.5294x; 1.5294x over previous
//
#include <hip/hip_runtime.h>
#include <hip/hip_bf16.h>

// R-GCN 2-layer forward, round-16: REVERT to round-10 (best, 531us) after
// fusion refuted 3x (412/336/316us vs split 204us/layer) — the bf16 ACC
// round-trip decouples gather latency from MFMA and beats every coupling.
// One contained change vs round-10: passB runs 512 threads (was 256) —
// grid is only 196 WGs (0.77/CU), so each WG's two serial 8K-edge passes
// halve and resident waves double on the active CUs.

#define D 128
#define KTOT 1152
#define KACC 1024
#define BK 32
#define BSH 9            // log2(coarse bucket size in nodes)
#define BSZ 512          // nodes per coarse bucket
#define TILE 4096        // edges per scatterA WG

typedef __attribute__((ext_vector_type(8))) __bf16 bf16x8;
typedef __attribute__((ext_vector_type(8))) unsigned short us8;
typedef __attribute__((ext_vector_type(4))) unsigned short us4;
typedef __attribute__((ext_vector_type(4))) float f32x4;

__device__ __forceinline__ unsigned short f2bf(float f) {
    union { float f; unsigned u; } v; v.f = f;
    unsigned r = v.u + 0x7FFF + ((v.u >> 16) & 1);   // RNE
    return (unsigned short)(r >> 16);
}
__device__ __forceinline__ float bf2f(unsigned short u) {
    return __uint_as_float((unsigned)u << 16);
}

__device__ __forceinline__ int lds_off(int row, int c) {
    return row * 32 + ((c ^ ((row >> 1) & 3)) << 3);
}

// ---------------- sort pass A: coarse-bucket histogram / scan / tile-sorted scatter ----------------

__global__ __launch_bounds__(256) void histA_kernel(const int* __restrict__ dst,
                                                    int* __restrict__ bcnt, int E, int nbuck) {
    __shared__ int c[1024];
    int t = threadIdx.x;
    for (int i = t; i < nbuck; i += 256) c[i] = 0;
    __syncthreads();
    int stride = gridDim.x * 256;
    for (int e = blockIdx.x * 256 + t; e < E; e += stride)
        atomicAdd(&c[dst[e] >> BSH], 1);
    __syncthreads();
    for (int i = t; i < nbuck; i += 256)
        if (c[i]) atomicAdd(&bcnt[i], c[i]);
}

__global__ __launch_bounds__(1024) void scanA_kernel(const int* __restrict__ bcnt,
                                                     int* __restrict__ boffs,
                                                     int* __restrict__ bhead, int nbuck) {
    int t = threadIdx.x;
    int v = (t < nbuck) ? bcnt[t] : 0;
    int lane = t & 63, w = t >> 6;
    int inc = v;
    #pragma unroll
    for (int off = 1; off < 64; off <<= 1) {
        int n = __shfl_up(inc, off, 64);
        if (lane >= off) inc += n;
    }
    __shared__ int ws[16];
    if (lane == 63) ws[w] = inc;
    __syncthreads();
    int wbase = 0;
    for (int i = 0; i < w; ++i) wbase += ws[i];
    int ex = wbase + inc - v;
    if (t < nbuck) { boffs[t] = ex; bhead[t] = ex; }
    if (t == nbuck - 1) boffs[nbuck] = ex + v;
}

// tile = 4096 edges per WG, 1024 threads (4 edges/thread): LDS counting-sort by
// coarse bucket, then write the reordered tile in per-bucket runs (~21 edges).
__global__ __launch_bounds__(1024) void scatterA_kernel(const int* __restrict__ src,
                                                        const int* __restrict__ dst,
                                                        const int* __restrict__ et,
                                                        int* __restrict__ bhead,
                                                        int* __restrict__ sortedA, int E, int nbuck) {
    __shared__ int skey[TILE];
    __shared__ unsigned char sbkt[TILE];
    __shared__ int cnt[256];
    __shared__ int lpos[256];
    __shared__ int gdelta[256];
    __shared__ int ws[4];
    const int t = threadIdx.x;
    const int e0 = blockIdx.x * TILE;
    int dreg[4];

    if (t < 256) cnt[t] = 0;
    __syncthreads();
    #pragma unroll
    for (int j = 0; j < 4; ++j) {
        int e = e0 + j * 1024 + t;
        int d = -1;
        if (e < E) { d = dst[e]; atomicAdd(&cnt[d >> BSH], 1); }
        dreg[j] = d;
    }
    __syncthreads();
    int c = 0, inc = 0;
    const int lane = t & 63, w = t >> 6;
    if (t < 256) {
        c = cnt[t];
        inc = c;
        #pragma unroll
        for (int off = 1; off < 64; off <<= 1) {
            int n = __shfl_up(inc, off, 64);
            if (lane >= off) inc += n;
        }
        if (lane == 63) ws[w] = inc;
    }
    __syncthreads();
    if (t < 256) {
        int wbase = 0;
        for (int i = 0; i < w; ++i) wbase += ws[i];
        int ex = wbase + inc - c;
        lpos[t] = ex;
        if (c) gdelta[t] = atomicAdd(&bhead[t], c) - ex;
    }
    __syncthreads();
    #pragma unroll
    for (int j = 0; j < 4; ++j) {
        int e = e0 + j * 1024 + t;
        if (e < E) {
            int d = dreg[j];
            int b = d >> BSH;
            int key = ((d & (BSZ - 1)) << 20) | (et[e] << 17) | src[e];
            int p = atomicAdd(&lpos[b], 1);
            skey[p] = key;
            sbkt[p] = (unsigned char)b;
        }
    }
    __syncthreads();
    int ntile = min(TILE, E - e0);
    for (int i = t; i < ntile; i += 1024)
        sortedA[gdelta[sbkt[i]] + i] = skey[i];
}

// ---------------- sort pass B: per-bucket fine sort by (node,rel) -> offs2[] + sorted[] ----------------
// 512 threads (round-16): grid is only 196 WGs, so intra-WG parallelism is the
// only lever — both serial passes halve vs the 256-thread version.

__global__ __launch_bounds__(512) void passB_kernel(const int* __restrict__ sortedA,
                                                    const int* __restrict__ boffs,
                                                    int* __restrict__ sorted,
                                                    int* __restrict__ offs2,
                                                    int N8, int E, int nbuck) {
    __shared__ int cnt[4096];
    __shared__ int cur[4096];
    __shared__ int ws[8];
    const int b = blockIdx.x;
    const int t = threadIdx.x;          // 0..511
    const int gb0 = boffs[b], gb1 = boffs[b + 1];
    #pragma unroll
    for (int i = 0; i < 8; ++i) cnt[i * 512 + t] = 0;
    __syncthreads();
    for (int e = gb0 + t; e < gb1; e += 512) {
        int k = sortedA[e];
        atomicAdd(&cnt[(k >> 17) & 4095], 1);   // (dst_low << 3) | etype
    }
    __syncthreads();
    const int base = t * 8;             // 512 threads x 8 counters
    int s = 0;
    #pragma unroll
    for (int i = 0; i < 8; ++i) s += cnt[base + i];
    int lane = t & 63, w = t >> 6;      // w: 0..7
    int inc = s;
    #pragma unroll
    for (int off = 1; off < 64; off <<= 1) {
        int n = __shfl_up(inc, off, 64);
        if (lane >= off) inc += n;
    }
    if (lane == 63) ws[w] = inc;
    __syncthreads();
    int wbase = 0;
    for (int i = 0; i < w; ++i) wbase += ws[i];
    int run = gb0 + wbase + inc - s;
    int g0 = (b << 12) + base;
    #pragma unroll
    for (int i = 0; i < 8; ++i) {
        int cv = cnt[base + i];
        cur[base + i] = run;
        if (g0 + i <= N8) offs2[g0 + i] = run;
        run += cv;
    }
    __syncthreads();
    // final scatter: all writes land inside this bucket's ~32KB window (L2-hot) -> no amplification
    for (int e = gb0 + t; e < gb1; e += 512) {
        int k = sortedA[e];
        int p = atomicAdd(&cur[(k >> 17) & 4095], 1);
        sorted[p] = k;
    }
}

// ---------------- combined cast: Bt[o][k] bf16 (both layers) + hb0 bf16 ----------------

__global__ void cast_kernel(const float* __restrict__ W1, const float* __restrict__ lw1,
                            const float* __restrict__ W2, const float* __restrict__ lw2,
                            const float* __restrict__ feats,
                            unsigned short* __restrict__ Bt1, unsigned short* __restrict__ Bt2,
                            unsigned short* __restrict__ hb0, int n4) {
    const int per = KTOT * D;          // 147456
    int idx = blockIdx.x * blockDim.x + threadIdx.x;
    if (idx < 2 * per) {
        int layer = idx / per;
        int rem = idx - layer * per;
        int k = rem >> 7;
        int o = rem & 127;             // coalesced read dim
        const float* W  = layer ? W2 : W1;
        const float* lw = layer ? lw2 : lw1;
        float val = (k < 1024) ? W[k * D + o] : lw[(k - 1024) * D + o];
        unsigned short* Bt = layer ? Bt2 : Bt1;
        Bt[o * KTOT + k] = f2bf(val);
    } else {
        int i = idx - 2 * per;
        if (i < n4) {
            float4 v = *(const float4*)(feats + (size_t)i * 4);
            us4 o; o.x = f2bf(v.x); o.y = f2bf(v.y); o.z = f2bf(v.z); o.w = f2bf(v.w);
            *(us4*)(hb0 + (size_t)i * 4) = o;
        }
    }
}

// ---------------- aggregation: one (node,rel) SEGMENT per 16-lane unit ----------------

__global__ __launch_bounds__(256) void aggregate_kernel(const unsigned short* __restrict__ hb,
                                                        const int* __restrict__ offs2,
                                                        const int* __restrict__ sorted,
                                                        unsigned short* __restrict__ A,
                                                        int v0, int vend) {
    const int t = threadIdx.x;
    const int c = (t & 15) * 8;            // 8 bf16 cols per lane
    const int gu = blockIdx.x * 16 + (t >> 4);
    const int v = v0 + (gu >> 3);
    const int r = gu & 7;
    if (v >= vend) return;

    const int e0 = offs2[v * 8 + r];
    const int e1 = offs2[v * 8 + r + 1];

    float a0[8], a1[8];
    #pragma unroll
    for (int j = 0; j < 8; ++j) { a0[j] = 0.f; a1[j] = 0.f; }

    int e = e0;
    for (; e + 1 < e1; e += 2) {
        int p0 = sorted[e], p1 = sorted[e + 1];
        us8 h0 = *(const us8*)(hb + (size_t)(p0 & 131071) * D + c);
        us8 h1 = *(const us8*)(hb + (size_t)(p1 & 131071) * D + c);
        #pragma unroll
        for (int j = 0; j < 8; ++j) { a0[j] += bf2f(h0[j]); a1[j] += bf2f(h1[j]); }
    }
    if (e < e1) {
        int p0 = sorted[e];
        us8 h0 = *(const us8*)(hb + (size_t)(p0 & 131071) * D + c);
        #pragma unroll
        for (int j = 0; j < 8; ++j) a0[j] += bf2f(h0[j]);
    }

    us8 o;
    #pragma unroll
    for (int j = 0; j < 8; ++j) o[j] = f2bf(a0[j] + a1[j]);
    *(us8*)(A + (size_t)(v - v0) * KACC + r * 128 + c) = o;
}

// ---------------- GEMM: out[v0:vend][128] = [ACC | hb_self] @ Bt^T + bias (+ReLU) ----------------
// BM=64 (782 WGs/chunk), register prefetch distance 1. (round-10 version —
// BM=32/128, LDS-free, and nt variants all refuted.)

__global__ __launch_bounds__(256) void gemm_kernel(const unsigned short* __restrict__ A,
                                                   const unsigned short* __restrict__ hbA,
                                                   const unsigned short* __restrict__ Bt,
                                                   const float* __restrict__ bias,
                                                   float* __restrict__ outf,
                                                   unsigned short* __restrict__ outb,
                                                   int v0, int vend, int relu_bf) {
    __shared__ unsigned short Alds[64 * 32];
    __shared__ unsigned short Blds[128 * 32];
    const int t = threadIdx.x;
    const int lane = t & 63;
    const int w = t >> 6;
    const int quad = lane >> 4;
    const int c16 = lane & 15;
    const int blockRow0 = v0 + blockIdx.x * 64;

    const int srow = t >> 2;           // 0..63
    const int schunk = t & 3;

    f32x4 acc[8];
    #pragma unroll
    for (int j = 0; j < 8; ++j) acc[j] = f32x4{0.f, 0.f, 0.f, 0.f};

    const int aRow = blockRow0 + srow;
    const bool aval = aRow < vend;
    const us8 zz = {0, 0, 0, 0, 0, 0, 0, 0};
    const unsigned short* Arow = A + (size_t)(aRow - v0) * KACC + schunk * 8;
    const unsigned short* Hrow = hbA + (size_t)aRow * D + schunk * 8;
    const unsigned short* Brow0 = Bt + (size_t)srow * KTOT + schunk * 8;
    const unsigned short* Brow1 = Bt + (size_t)(srow + 64) * KTOT + schunk * 8;

    // prologue: prefetch K-step 0
    us8 av = zz;
    if (aval) av = *(const us8*)(Arow);
    us8 bv0 = *(const us8*)(Brow0);
    us8 bv1 = *(const us8*)(Brow1);

    for (int k0 = 0; k0 < KTOT; k0 += BK) {
        us8 na = zz, nb0 = zz, nb1 = zz;
        const int kn = k0 + BK;
        if (kn < KTOT) {
            if (aval) {
                if (kn < KACC) na = *(const us8*)(Arow + kn);
                else           na = *(const us8*)(Hrow + (kn - KACC));
            }
            nb0 = *(const us8*)(Brow0 + kn);
            nb1 = *(const us8*)(Brow1 + kn);
        }
        __syncthreads();
        *(us8*)(Alds + lds_off(srow, schunk)) = av;
        *(us8*)(Blds + lds_off(srow,      schunk)) = bv0;
        *(us8*)(Blds + lds_off(srow + 64, schunk)) = bv1;
        __syncthreads();

        bf16x8 af = *(const bf16x8*)(Alds + lds_off(w * 16 + c16, quad));
        #pragma unroll
        for (int ct = 0; ct < 8; ++ct) {
            bf16x8 bfr = *(const bf16x8*)(Blds + lds_off(ct * 16 + c16, quad));
            acc[ct] = __builtin_amdgcn_mfma_f32_16x16x32_bf16(af, bfr, acc[ct], 0, 0, 0);
        }
        av = na; bv0 = nb0; bv1 = nb1;
    }

    // epilogue: C[row=quad*4+i][col=c16] per 16x16 tile
    int row = blockRow0 + w * 16 + quad * 4;
    #pragma unroll
    for (int ct = 0; ct < 8; ++ct) {
        int col = ct * 16 + c16;
        float bcol = bias[col];
        #pragma unroll
        for (int i = 0; i < 4; ++i) {
            int r = row + i;
            if (r < vend) {
                float vv = acc[ct][i] + bcol;
                if (relu_bf) {
                    vv = fmaxf(vv, 0.f);
                    outb[(size_t)r * D + col] = f2bf(vv);
                } else {
                    outf[(size_t)r * D + col] = vv;
                }
            }
        }
    }
}

// ---------------- launch ----------------

extern "C" void kernel_launch(void* const* d_in, const int* in_sizes, int n_in,
                              void* d_out, int out_size, void* d_ws, size_t ws_size,
                              hipStream_t stream) {
    const float* feats = (const float*)d_in[0];
    const float* W1    = (const float*)d_in[1];
    const float* lw1   = (const float*)d_in[2];
    const float* b1    = (const float*)d_in[3];
    const float* W2    = (const float*)d_in[4];
    const float* lw2   = (const float*)d_in[5];
    const float* b2    = (const float*)d_in[6];
    const int*   src   = (const int*)d_in[7];
    const int*   dst   = (const int*)d_in[8];
    const int*   etype = (const int*)d_in[9];
    const int N = in_sizes[0] / D;
    const int E = in_sizes[7];
    float* out = (float*)d_out;

    const int ch = (N + 1) / 2;           // node chunk size (2 chunks)
    const int nbuck = (N + BSZ - 1) >> BSH;

    size_t woff = 0;
    auto take = [&](size_t bytes) -> void* {
        void* p = (char*)d_ws + woff;
        woff += (bytes + 255) & ~(size_t)255;
        return p;
    };
    int* bcnt           = (int*)take((size_t)1024 * 4);
    int* boffs          = (int*)take((size_t)1025 * 4);
    int* bhead          = (int*)take((size_t)1024 * 4);
    int* offs2          = (int*)take((size_t)(N * 8 + 1) * 4);
    int* sortedA        = (int*)take((size_t)E * 4);
    int* sorted         = (int*)take((size_t)E * 4);
    unsigned short* Bt1 = (unsigned short*)take((size_t)KTOT * D * 2);
    unsigned short* Bt2 = (unsigned short*)take((size_t)KTOT * D * 2);
    unsigned short* hb0 = (unsigned short*)take((size_t)N * D * 2);
    unsigned short* hb1 = (unsigned short*)take((size_t)N * D * 2);
    unsigned short* ACC = (unsigned short*)take((size_t)ch * KACC * 2);   // ~102 MB

    (void)hipMemsetAsync(bcnt, 0, (size_t)nbuck * 4, stream);

    histA_kernel<<<1024, 256, 0, stream>>>(dst, bcnt, E, nbuck);
    scanA_kernel<<<1, 1024, 0, stream>>>(bcnt, boffs, bhead, nbuck);
    scatterA_kernel<<<(E + TILE - 1) / TILE, 1024, 0, stream>>>(src, dst, etype, bhead, sortedA, E, nbuck);
    passB_kernel<<<nbuck, 512, 0, stream>>>(sortedA, boffs, sorted, offs2, N * 8, E, nbuck);

    int n4 = N * D / 4;
    int cb = (2 * KTOT * D + n4 + 255) / 256;
    cast_kernel<<<cb, 256, 0, stream>>>(W1, lw1, W2, lw2, feats, Bt1, Bt2, hb0, n4);

    for (int layer = 0; layer < 2; ++layer) {
        const unsigned short* hin = layer ? hb1 : hb0;
        const unsigned short* Bt  = layer ? Bt2 : Bt1;
        const float* bias         = layer ? b2  : b1;
        for (int c0 = 0; c0 < N; c0 += ch) {
            int c1 = (c0 + ch < N) ? (c0 + ch) : N;
            int len = c1 - c0;
            int ab = (len * 8 + 15) / 16;   // one (node,rel) segment per 16-lane unit
            int gb = (len + 63) / 64;
            aggregate_kernel<<<ab, 256, 0, stream>>>(hin, offs2, sorted, ACC, c0, c1);
            gemm_kernel<<<gb, 256, 0, stream>>>(ACC, hin, Bt, bias, out, hb1, c0, c1, 1 - layer);
        }
    }
}

// Round 15
// 506.038 us; speedup vs baseline: 1.5780x; 1.0318x over previous
//
#include <hip/hip_runtime.h>
#include <hip/hip_bf16.h>

// R-GCN 2-layer forward, round-17: round-16 (522us) minus CHUNKING.
// gemm was GRID-limited (782 WGs = 3 WG/CU, Occ 24%) because the 2-chunk loop
// halves every dispatch. Full-size ACC (204.8MB) fits the 256MiB workspace by
// aliasing the sort scratch (sortedA/bcnt/boffs/bhead — dead before aggregate)
// over ACC's head: total 266.2MB < 268.4MB. One aggregate + one gemm dispatch
// per layer: gemm 1563 WGs (6 WG/CU), aggregate 50000 WGs, 4 fewer launches.
// All kernels byte-identical to round-16 (passB@512 kept).

#define D 128
#define KTOT 1152
#define KACC 1024
#define BK 32
#define BSH 9            // log2(coarse bucket size in nodes)
#define BSZ 512          // nodes per coarse bucket
#define TILE 4096        // edges per scatterA WG

typedef __attribute__((ext_vector_type(8))) __bf16 bf16x8;
typedef __attribute__((ext_vector_type(8))) unsigned short us8;
typedef __attribute__((ext_vector_type(4))) unsigned short us4;
typedef __attribute__((ext_vector_type(4))) float f32x4;

__device__ __forceinline__ unsigned short f2bf(float f) {
    union { float f; unsigned u; } v; v.f = f;
    unsigned r = v.u + 0x7FFF + ((v.u >> 16) & 1);   // RNE
    return (unsigned short)(r >> 16);
}
__device__ __forceinline__ float bf2f(unsigned short u) {
    return __uint_as_float((unsigned)u << 16);
}

__device__ __forceinline__ int lds_off(int row, int c) {
    return row * 32 + ((c ^ ((row >> 1) & 3)) << 3);
}

// ---------------- sort pass A: coarse-bucket histogram / scan / tile-sorted scatter ----------------

__global__ __launch_bounds__(256) void histA_kernel(const int* __restrict__ dst,
                                                    int* __restrict__ bcnt, int E, int nbuck) {
    __shared__ int c[1024];
    int t = threadIdx.x;
    for (int i = t; i < nbuck; i += 256) c[i] = 0;
    __syncthreads();
    int stride = gridDim.x * 256;
    for (int e = blockIdx.x * 256 + t; e < E; e += stride)
        atomicAdd(&c[dst[e] >> BSH], 1);
    __syncthreads();
    for (int i = t; i < nbuck; i += 256)
        if (c[i]) atomicAdd(&bcnt[i], c[i]);
}

__global__ __launch_bounds__(1024) void scanA_kernel(const int* __restrict__ bcnt,
                                                     int* __restrict__ boffs,
                                                     int* __restrict__ bhead, int nbuck) {
    int t = threadIdx.x;
    int v = (t < nbuck) ? bcnt[t] : 0;
    int lane = t & 63, w = t >> 6;
    int inc = v;
    #pragma unroll
    for (int off = 1; off < 64; off <<= 1) {
        int n = __shfl_up(inc, off, 64);
        if (lane >= off) inc += n;
    }
    __shared__ int ws[16];
    if (lane == 63) ws[w] = inc;
    __syncthreads();
    int wbase = 0;
    for (int i = 0; i < w; ++i) wbase += ws[i];
    int ex = wbase + inc - v;
    if (t < nbuck) { boffs[t] = ex; bhead[t] = ex; }
    if (t == nbuck - 1) boffs[nbuck] = ex + v;
}

// tile = 4096 edges per WG, 1024 threads (4 edges/thread): LDS counting-sort by
// coarse bucket, then write the reordered tile in per-bucket runs (~21 edges).
__global__ __launch_bounds__(1024) void scatterA_kernel(const int* __restrict__ src,
                                                        const int* __restrict__ dst,
                                                        const int* __restrict__ et,
                                                        int* __restrict__ bhead,
                                                        int* __restrict__ sortedA, int E, int nbuck) {
    __shared__ int skey[TILE];
    __shared__ unsigned char sbkt[TILE];
    __shared__ int cnt[256];
    __shared__ int lpos[256];
    __shared__ int gdelta[256];
    __shared__ int ws[4];
    const int t = threadIdx.x;
    const int e0 = blockIdx.x * TILE;
    int dreg[4];

    if (t < 256) cnt[t] = 0;
    __syncthreads();
    #pragma unroll
    for (int j = 0; j < 4; ++j) {
        int e = e0 + j * 1024 + t;
        int d = -1;
        if (e < E) { d = dst[e]; atomicAdd(&cnt[d >> BSH], 1); }
        dreg[j] = d;
    }
    __syncthreads();
    int c = 0, inc = 0;
    const int lane = t & 63, w = t >> 6;
    if (t < 256) {
        c = cnt[t];
        inc = c;
        #pragma unroll
        for (int off = 1; off < 64; off <<= 1) {
            int n = __shfl_up(inc, off, 64);
            if (lane >= off) inc += n;
        }
        if (lane == 63) ws[w] = inc;
    }
    __syncthreads();
    if (t < 256) {
        int wbase = 0;
        for (int i = 0; i < w; ++i) wbase += ws[i];
        int ex = wbase + inc - c;
        lpos[t] = ex;
        if (c) gdelta[t] = atomicAdd(&bhead[t], c) - ex;
    }
    __syncthreads();
    #pragma unroll
    for (int j = 0; j < 4; ++j) {
        int e = e0 + j * 1024 + t;
        if (e < E) {
            int d = dreg[j];
            int b = d >> BSH;
            int key = ((d & (BSZ - 1)) << 20) | (et[e] << 17) | src[e];
            int p = atomicAdd(&lpos[b], 1);
            skey[p] = key;
            sbkt[p] = (unsigned char)b;
        }
    }
    __syncthreads();
    int ntile = min(TILE, E - e0);
    for (int i = t; i < ntile; i += 1024)
        sortedA[gdelta[sbkt[i]] + i] = skey[i];
}

// ---------------- sort pass B: per-bucket fine sort by (node,rel) -> offs2[] + sorted[] ----------------
// 512 threads: grid is only 196 WGs, so intra-WG parallelism is the lever.

__global__ __launch_bounds__(512) void passB_kernel(const int* __restrict__ sortedA,
                                                    const int* __restrict__ boffs,
                                                    int* __restrict__ sorted,
                                                    int* __restrict__ offs2,
                                                    int N8, int E, int nbuck) {
    __shared__ int cnt[4096];
    __shared__ int cur[4096];
    __shared__ int ws[8];
    const int b = blockIdx.x;
    const int t = threadIdx.x;          // 0..511
    const int gb0 = boffs[b], gb1 = boffs[b + 1];
    #pragma unroll
    for (int i = 0; i < 8; ++i) cnt[i * 512 + t] = 0;
    __syncthreads();
    for (int e = gb0 + t; e < gb1; e += 512) {
        int k = sortedA[e];
        atomicAdd(&cnt[(k >> 17) & 4095], 1);   // (dst_low << 3) | etype
    }
    __syncthreads();
    const int base = t * 8;             // 512 threads x 8 counters
    int s = 0;
    #pragma unroll
    for (int i = 0; i < 8; ++i) s += cnt[base + i];
    int lane = t & 63, w = t >> 6;      // w: 0..7
    int inc = s;
    #pragma unroll
    for (int off = 1; off < 64; off <<= 1) {
        int n = __shfl_up(inc, off, 64);
        if (lane >= off) inc += n;
    }
    if (lane == 63) ws[w] = inc;
    __syncthreads();
    int wbase = 0;
    for (int i = 0; i < w; ++i) wbase += ws[i];
    int run = gb0 + wbase + inc - s;
    int g0 = (b << 12) + base;
    #pragma unroll
    for (int i = 0; i < 8; ++i) {
        int cv = cnt[base + i];
        cur[base + i] = run;
        if (g0 + i <= N8) offs2[g0 + i] = run;
        run += cv;
    }
    __syncthreads();
    // final scatter: all writes land inside this bucket's ~32KB window (L2-hot) -> no amplification
    for (int e = gb0 + t; e < gb1; e += 512) {
        int k = sortedA[e];
        int p = atomicAdd(&cur[(k >> 17) & 4095], 1);
        sorted[p] = k;
    }
}

// ---------------- combined cast: Bt[o][k] bf16 (both layers) + hb0 bf16 ----------------

__global__ void cast_kernel(const float* __restrict__ W1, const float* __restrict__ lw1,
                            const float* __restrict__ W2, const float* __restrict__ lw2,
                            const float* __restrict__ feats,
                            unsigned short* __restrict__ Bt1, unsigned short* __restrict__ Bt2,
                            unsigned short* __restrict__ hb0, int n4) {
    const int per = KTOT * D;          // 147456
    int idx = blockIdx.x * blockDim.x + threadIdx.x;
    if (idx < 2 * per) {
        int layer = idx / per;
        int rem = idx - layer * per;
        int k = rem >> 7;
        int o = rem & 127;             // coalesced read dim
        const float* W  = layer ? W2 : W1;
        const float* lw = layer ? lw2 : lw1;
        float val = (k < 1024) ? W[k * D + o] : lw[(k - 1024) * D + o];
        unsigned short* Bt = layer ? Bt2 : Bt1;
        Bt[o * KTOT + k] = f2bf(val);
    } else {
        int i = idx - 2 * per;
        if (i < n4) {
            float4 v = *(const float4*)(feats + (size_t)i * 4);
            us4 o; o.x = f2bf(v.x); o.y = f2bf(v.y); o.z = f2bf(v.z); o.w = f2bf(v.w);
            *(us4*)(hb0 + (size_t)i * 4) = o;
        }
    }
}

// ---------------- aggregation: one (node,rel) SEGMENT per 16-lane unit ----------------

__global__ __launch_bounds__(256) void aggregate_kernel(const unsigned short* __restrict__ hb,
                                                        const int* __restrict__ offs2,
                                                        const int* __restrict__ sorted,
                                                        unsigned short* __restrict__ A,
                                                        int v0, int vend) {
    const int t = threadIdx.x;
    const int c = (t & 15) * 8;            // 8 bf16 cols per lane
    const int gu = blockIdx.x * 16 + (t >> 4);
    const int v = v0 + (gu >> 3);
    const int r = gu & 7;
    if (v >= vend) return;

    const int e0 = offs2[v * 8 + r];
    const int e1 = offs2[v * 8 + r + 1];

    float a0[8], a1[8];
    #pragma unroll
    for (int j = 0; j < 8; ++j) { a0[j] = 0.f; a1[j] = 0.f; }

    int e = e0;
    for (; e + 1 < e1; e += 2) {
        int p0 = sorted[e], p1 = sorted[e + 1];
        us8 h0 = *(const us8*)(hb + (size_t)(p0 & 131071) * D + c);
        us8 h1 = *(const us8*)(hb + (size_t)(p1 & 131071) * D + c);
        #pragma unroll
        for (int j = 0; j < 8; ++j) { a0[j] += bf2f(h0[j]); a1[j] += bf2f(h1[j]); }
    }
    if (e < e1) {
        int p0 = sorted[e];
        us8 h0 = *(const us8*)(hb + (size_t)(p0 & 131071) * D + c);
        #pragma unroll
        for (int j = 0; j < 8; ++j) a0[j] += bf2f(h0[j]);
    }

    us8 o;
    #pragma unroll
    for (int j = 0; j < 8; ++j) o[j] = f2bf(a0[j] + a1[j]);
    *(us8*)(A + (size_t)(v - v0) * KACC + r * 128 + c) = o;
}

// ---------------- GEMM: out[0:N][128] = [ACC | hb_self] @ Bt^T + bias (+ReLU) ----------------
// BM=64, full grid (1563 WGs = 6 WG/CU), register prefetch distance 1.

__global__ __launch_bounds__(256) void gemm_kernel(const unsigned short* __restrict__ A,
                                                   const unsigned short* __restrict__ hbA,
                                                   const unsigned short* __restrict__ Bt,
                                                   const float* __restrict__ bias,
                                                   float* __restrict__ outf,
                                                   unsigned short* __restrict__ outb,
                                                   int v0, int vend, int relu_bf) {
    __shared__ unsigned short Alds[64 * 32];
    __shared__ unsigned short Blds[128 * 32];
    const int t = threadIdx.x;
    const int lane = t & 63;
    const int w = t >> 6;
    const int quad = lane >> 4;
    const int c16 = lane & 15;
    const int blockRow0 = v0 + blockIdx.x * 64;

    const int srow = t >> 2;           // 0..63
    const int schunk = t & 3;

    f32x4 acc[8];
    #pragma unroll
    for (int j = 0; j < 8; ++j) acc[j] = f32x4{0.f, 0.f, 0.f, 0.f};

    const int aRow = blockRow0 + srow;
    const bool aval = aRow < vend;
    const us8 zz = {0, 0, 0, 0, 0, 0, 0, 0};
    const unsigned short* Arow = A + (size_t)(aRow - v0) * KACC + schunk * 8;
    const unsigned short* Hrow = hbA + (size_t)aRow * D + schunk * 8;
    const unsigned short* Brow0 = Bt + (size_t)srow * KTOT + schunk * 8;
    const unsigned short* Brow1 = Bt + (size_t)(srow + 64) * KTOT + schunk * 8;

    // prologue: prefetch K-step 0
    us8 av = zz;
    if (aval) av = *(const us8*)(Arow);
    us8 bv0 = *(const us8*)(Brow0);
    us8 bv1 = *(const us8*)(Brow1);

    for (int k0 = 0; k0 < KTOT; k0 += BK) {
        us8 na = zz, nb0 = zz, nb1 = zz;
        const int kn = k0 + BK;
        if (kn < KTOT) {
            if (aval) {
                if (kn < KACC) na = *(const us8*)(Arow + kn);
                else           na = *(const us8*)(Hrow + (kn - KACC));
            }
            nb0 = *(const us8*)(Brow0 + kn);
            nb1 = *(const us8*)(Brow1 + kn);
        }
        __syncthreads();
        *(us8*)(Alds + lds_off(srow, schunk)) = av;
        *(us8*)(Blds + lds_off(srow,      schunk)) = bv0;
        *(us8*)(Blds + lds_off(srow + 64, schunk)) = bv1;
        __syncthreads();

        bf16x8 af = *(const bf16x8*)(Alds + lds_off(w * 16 + c16, quad));
        #pragma unroll
        for (int ct = 0; ct < 8; ++ct) {
            bf16x8 bfr = *(const bf16x8*)(Blds + lds_off(ct * 16 + c16, quad));
            acc[ct] = __builtin_amdgcn_mfma_f32_16x16x32_bf16(af, bfr, acc[ct], 0, 0, 0);
        }
        av = na; bv0 = nb0; bv1 = nb1;
    }

    // epilogue: C[row=quad*4+i][col=c16] per 16x16 tile
    int row = blockRow0 + w * 16 + quad * 4;
    #pragma unroll
    for (int ct = 0; ct < 8; ++ct) {
        int col = ct * 16 + c16;
        float bcol = bias[col];
        #pragma unroll
        for (int i = 0; i < 4; ++i) {
            int r = row + i;
            if (r < vend) {
                float vv = acc[ct][i] + bcol;
                if (relu_bf) {
                    vv = fmaxf(vv, 0.f);
                    outb[(size_t)r * D + col] = f2bf(vv);
                } else {
                    outf[(size_t)r * D + col] = vv;
                }
            }
        }
    }
}

// ---------------- launch ----------------

extern "C" void kernel_launch(void* const* d_in, const int* in_sizes, int n_in,
                              void* d_out, int out_size, void* d_ws, size_t ws_size,
                              hipStream_t stream) {
    const float* feats = (const float*)d_in[0];
    const float* W1    = (const float*)d_in[1];
    const float* lw1   = (const float*)d_in[2];
    const float* b1    = (const float*)d_in[3];
    const float* W2    = (const float*)d_in[4];
    const float* lw2   = (const float*)d_in[5];
    const float* b2    = (const float*)d_in[6];
    const int*   src   = (const int*)d_in[7];
    const int*   dst   = (const int*)d_in[8];
    const int*   etype = (const int*)d_in[9];
    const int N = in_sizes[0] / D;
    const int E = in_sizes[7];
    float* out = (float*)d_out;

    const int nbuck = (N + BSZ - 1) >> BSH;

    size_t woff = 0;
    auto take = [&](size_t bytes) -> void* {
        void* p = (char*)d_ws + woff;
        woff += (bytes + 255) & ~(size_t)255;
        return p;
    };
    // Full-size ACC first; sort scratch (dead before aggregate) aliases its head.
    unsigned short* ACC = (unsigned short*)take((size_t)N * KACC * 2);   // 204.8 MB
    int* sortedA        = (int*)ACC;                                     // E*4 = 6.4 MB
    int* bcnt           = (int*)((char*)ACC + (((size_t)E * 4 + 255) & ~(size_t)255));
    int* boffs          = bcnt + 1024;
    int* bhead          = boffs + 1032;
    // Persistent buffers (live across both layers):
    int* offs2          = (int*)take((size_t)(N * 8 + 1) * 4);
    int* sorted         = (int*)take((size_t)E * 4);
    unsigned short* Bt1 = (unsigned short*)take((size_t)KTOT * D * 2);
    unsigned short* Bt2 = (unsigned short*)take((size_t)KTOT * D * 2);
    unsigned short* hb0 = (unsigned short*)take((size_t)N * D * 2);
    unsigned short* hb1 = (unsigned short*)take((size_t)N * D * 2);

    (void)hipMemsetAsync(bcnt, 0, (size_t)nbuck * 4, stream);

    histA_kernel<<<1024, 256, 0, stream>>>(dst, bcnt, E, nbuck);
    scanA_kernel<<<1, 1024, 0, stream>>>(bcnt, boffs, bhead, nbuck);
    scatterA_kernel<<<(E + TILE - 1) / TILE, 1024, 0, stream>>>(src, dst, etype, bhead, sortedA, E, nbuck);
    passB_kernel<<<nbuck, 512, 0, stream>>>(sortedA, boffs, sorted, offs2, N * 8, E, nbuck);

    int n4 = N * D / 4;
    int cb = (2 * KTOT * D + n4 + 255) / 256;
    cast_kernel<<<cb, 256, 0, stream>>>(W1, lw1, W2, lw2, feats, Bt1, Bt2, hb0, n4);

    int ab = (N * 8 + 15) / 16;        // one (node,rel) segment per 16-lane unit
    int gb = (N + 63) / 64;
    for (int layer = 0; layer < 2; ++layer) {
        const unsigned short* hin = layer ? hb1 : hb0;
        const unsigned short* Bt  = layer ? Bt2 : Bt1;
        const float* bias         = layer ? b2  : b1;
        aggregate_kernel<<<ab, 256, 0, stream>>>(hin, offs2, sorted, ACC, 0, N);
        gemm_kernel<<<gb, 256, 0, stream>>>(ACC, hin, Bt, bias, out, hb1, 0, N, 1 - layer);
    }
}